// Round 8
// baseline (84.761 us; speedup 1.0000x reference)
//
#include <hip/hip_runtime.h>

#define N_NODES 50000
#define N_EDGES 100000
#define NUM_RELS 200
#define DIM 64
#define CAP 512
#define TILES 8          // CAP/64 tiles per rel
#define HPAD 68          // padded transposed-H stride (floats); 272B keeps 16B align

// ---- workspace layout (int32 elements) ----
#define OFF_LAST 0
#define OFF_CUR  50000
#define OFF_BN   50200
#define OFF_BS   (50200 + NUM_RELS * CAP)

#define NODE_TILES 782   // ceil(50000/64)

__global__ void init_kernel(int* __restrict__ ws) {
    int i = blockIdx.x * 256 + threadIdx.x;
    if (i < N_NODES) ws[OFF_LAST + i] = -1;
    if (i < NUM_RELS) ws[OFF_CUR + i] = 0;
}

__global__ void edge_max_kernel(const int* __restrict__ edges, int* __restrict__ ws) {
    int e = blockIdx.x * 256 + threadIdx.x;
    if (e < N_EDGES) atomicMax(&ws[OFF_LAST + edges[e * 3 + 2]], e);
}

// Stage 64x64 W into LDS: 16 coalesced float4 per lane (64 lanes).
__device__ __forceinline__ void stage_w(const float* __restrict__ Wsrc,
                                        float* __restrict__ Wl, int lane) {
    const float4* wg = (const float4*)Wsrc;
    float4* wl4 = (float4*)Wl;
#pragma unroll
    for (int j = 0; j < 16; ++j) wl4[lane + j * 64] = wg[lane + j * 64];
}

// Stage one h row (lane = entry) transposed into Hl[k][entry].
__device__ __forceinline__ void stage_h(const float* __restrict__ hrow,
                                        float* __restrict__ Hl, int lane) {
    const float4* hg = (const float4*)hrow;
#pragma unroll
    for (int j = 0; j < 16; ++j) {
        float4 v = hg[j];
        int k0 = j * 4;
        Hl[(k0 + 0) * HPAD + lane] = v.x;
        Hl[(k0 + 1) * HPAD + lane] = v.y;
        Hl[(k0 + 2) * HPAD + lane] = v.z;
        Hl[(k0 + 3) * HPAD + lane] = v.w;
    }
}

// One wave computes the full 64x64 tile: thread = 8 entries x 8 cols.
__device__ __forceinline__ void gemm88(const float* __restrict__ Hl,
                                       const float* __restrict__ Wl,
                                       int e8, int c8, float acc[8][8]) {
#pragma unroll 2
    for (int k = 0; k < DIM; ++k) {
        float4 ha = *(const float4*)&Hl[k * HPAD + e8 * 8];
        float4 hb = *(const float4*)&Hl[k * HPAD + e8 * 8 + 4];
        float4 wa = *(const float4*)&Wl[k * DIM + c8 * 8];
        float4 wb = *(const float4*)&Wl[k * DIM + c8 * 8 + 4];
        float hv[8] = {ha.x, ha.y, ha.z, ha.w, hb.x, hb.y, hb.z, hb.w};
        float wv[8] = {wa.x, wa.y, wa.z, wa.w, wb.x, wb.y, wb.z, wb.w};
#pragma unroll
        for (int i = 0; i < 8; ++i)
#pragma unroll
            for (int j = 0; j < 8; ++j)
                acc[i][j] = fmaf(hv[i], wv[j], acc[i][j]);
    }
}

// Fused: blocks [0,NODE_TILES) bucket nodes by rel; blocks [NODE_TILES,2*NODE_TILES)
// compute out = h @ wself, one 64-node tile per single-wave block.
__global__ __launch_bounds__(64) void bucket_self_kernel(
    const float* __restrict__ h,
    const int* __restrict__ edges,
    const float* __restrict__ wself,
    int* __restrict__ ws,
    float* __restrict__ out)
{
    __shared__ float Wl[DIM * DIM];
    __shared__ float Hl[DIM * HPAD];
    int lane = threadIdx.x;

    if (blockIdx.x < NODE_TILES) {
        int n = blockIdx.x * 64 + lane;
        if (n < N_NODES) {
            int li = ws[OFF_LAST + n];
            if (li >= 0) {
                int r = edges[li * 3 + 1];
                int s = edges[li * 3 + 0];
                int pos = atomicAdd(&ws[OFF_CUR + r], 1);
                if (pos < CAP) {
                    ws[OFF_BN + r * CAP + pos] = n;
                    ws[OFF_BS + r * CAP + pos] = s;
                }
            }
        }
        return;
    }

    int base = (blockIdx.x - NODE_TILES) * 64;
    int n = base + lane;
    if (n >= N_NODES) n = N_NODES - 1;

    stage_w(wself, Wl, lane);
    stage_h(h + (size_t)n * DIM, Hl, lane);
    __syncthreads();

    int e8 = lane >> 3, c8 = lane & 7;
    float acc[8][8];
#pragma unroll
    for (int i = 0; i < 8; ++i)
#pragma unroll
        for (int j = 0; j < 8; ++j) acc[i][j] = 0.f;

    gemm88(Hl, Wl, e8, c8, acc);

#pragma unroll
    for (int i = 0; i < 8; ++i) {
        int nn = base + e8 * 8 + i;
        if (nn < N_NODES) {
            float* op = out + (size_t)nn * DIM + c8 * 8;
            *(float4*)op       = make_float4(acc[i][0], acc[i][1], acc[i][2], acc[i][3]);
            *(float4*)(op + 4) = make_float4(acc[i][4], acc[i][5], acc[i][6], acc[i][7]);
        }
    }
}

// msg: block = (rel, 64-entry tile), single wave; out[n] += h[src] @ weight[rel].
__global__ __launch_bounds__(64) void msg_kernel(const float* __restrict__ h,
                                                 const float* __restrict__ weight,
                                                 const int* __restrict__ ws,
                                                 float* __restrict__ out) {
    __shared__ float Wl[DIM * DIM];
    __shared__ float Hl[DIM * HPAD];

    int rel  = blockIdx.x >> 3;
    int tile = blockIdx.x & 7;
    int c = ws[OFF_CUR + rel];
    if (c > CAP) c = CAP;
    int start = tile * 64;
    if (start >= c) return;

    int lane = threadIdx.x;
    const int* bn = ws + OFF_BN + rel * CAP;
    const int* bs = ws + OFF_BS + rel * CAP;

    int pos = start + lane;
    int cp = pos < c ? pos : (c - 1);
    int s = bs[cp];

    stage_w(weight + (size_t)rel * DIM * DIM, Wl, lane);
    stage_h(h + (size_t)s * DIM, Hl, lane);
    __syncthreads();

    int e8 = lane >> 3, c8 = lane & 7;
    float acc[8][8];
#pragma unroll
    for (int i = 0; i < 8; ++i)
#pragma unroll
        for (int j = 0; j < 8; ++j) acc[i][j] = 0.f;

    gemm88(Hl, Wl, e8, c8, acc);

#pragma unroll
    for (int i = 0; i < 8; ++i) {
        int p = start + e8 * 8 + i;
        if (p < c) {
            int nn = bn[p];
            float* op = out + (size_t)nn * DIM + c8 * 8;
            float4 c0 = *(const float4*)op;
            float4 c1 = *(const float4*)(op + 4);
            *(float4*)op       = make_float4(c0.x + acc[i][0], c0.y + acc[i][1],
                                             c0.z + acc[i][2], c0.w + acc[i][3]);
            *(float4*)(op + 4) = make_float4(c1.x + acc[i][4], c1.y + acc[i][5],
                                             c1.z + acc[i][6], c1.w + acc[i][7]);
        }
    }
}

extern "C" void kernel_launch(void* const* d_in, const int* in_sizes, int n_in,
                              void* d_out, int out_size, void* d_ws, size_t ws_size,
                              hipStream_t stream) {
    const float* h      = (const float*)d_in[0];
    const int*   edges  = (const int*)d_in[1];
    const float* weight = (const float*)d_in[2];
    const float* wself  = (const float*)d_in[3];
    float* out = (float*)d_out;
    int* ws = (int*)d_ws;

    init_kernel<<<(N_NODES + 255) / 256, 256, 0, stream>>>(ws);
    edge_max_kernel<<<(N_EDGES + 255) / 256, 256, 0, stream>>>(edges, ws);
    bucket_self_kernel<<<NODE_TILES * 2, 64, 0, stream>>>(h, edges, wself, ws, out);
    msg_kernel<<<NUM_RELS * TILES, 64, 0, stream>>>(h, weight, ws, out);
}

// Round 9
// 59.780 us; speedup vs baseline: 1.4179x; 1.4179x over previous
//
#include <hip/hip_runtime.h>

#define N_NODES 50000
#define N_EDGES 100000
#define NUM_RELS 200
#define DIM 64
#define CAP 512
#define TILES 8
#define KPAD 72            // padded K-stride in ushorts (144B): balanced banks, 16B aligned

typedef __attribute__((ext_vector_type(8))) short bf16x8;
typedef __attribute__((ext_vector_type(8))) unsigned short u16x8;
typedef __attribute__((ext_vector_type(4))) float f32x4;

// ---- workspace layout ----
// int32 region:
#define OFF_LAST 0
#define OFF_CUR  50000
#define OFF_BN   50200
#define OFF_BS   152600          // 50200 + 200*512
// byte offsets (16B aligned):
#define HB_OFF   1020032u        // bf16 h: 50000*64 ushorts = 6.4 MB
#define WT_OFF   7420032u        // bf16 W^T: 201*64*64 ushorts (200 rels + wself at idx 200)

__device__ __forceinline__ unsigned short f2bf(float x) {
    union { float f; unsigned u; } v; v.f = x;
    unsigned r = v.u + 0x7FFFu + ((v.u >> 16) & 1u);   // RNE
    return (unsigned short)(r >> 16);
}

// ---------- prep: init last/cur + convert h -> bf16 + transpose/convert W -> bf16 K-major ----------
#define PREP_INIT 197            // ceil(50200/256)
#define PREP_WT   201            // 200 rels + wself
#define PREP_HB   782            // ceil(3.2M/4096)

__global__ __launch_bounds__(256) void prep_kernel(
    const float* __restrict__ h, const float* __restrict__ weight,
    const float* __restrict__ wself, int* __restrict__ ws,
    unsigned short* __restrict__ hb, unsigned short* __restrict__ wt)
{
    __shared__ float Wl[DIM * DIM];
    int b = blockIdx.x, t = threadIdx.x;

    if (b < PREP_INIT) {
        int i = b * 256 + t;
        if (i < N_NODES) ws[OFF_LAST + i] = -1;
        if (i < NUM_RELS) ws[OFF_CUR + i] = 0;
        return;
    }
    if (b < PREP_INIT + PREP_WT) {
        int rel = b - PREP_INIT;
        const float* src = (rel < NUM_RELS) ? (weight + (size_t)rel * DIM * DIM) : wself;
#pragma unroll
        for (int j = 0; j < 16; ++j) Wl[t + j * 256] = src[t + j * 256];
        __syncthreads();
        int c = t >> 2, q = t & 3;          // col, k-quarter
        unsigned short tmp[16];
#pragma unroll
        for (int kk = 0; kk < 16; ++kk)
            tmp[kk] = f2bf(Wl[(q * 16 + kk) * DIM + c]);
        unsigned short* dst = wt + (size_t)rel * DIM * DIM + c * DIM + q * 16;
        *(u16x8*)dst       = *(const u16x8*)&tmp[0];
        *(u16x8*)(dst + 8) = *(const u16x8*)&tmp[8];
        return;
    }
    {
        long off = (long)(b - PREP_INIT - PREP_WT) * 4096 + (long)t * 16;
        if (off < (long)N_NODES * DIM) {
            const float4* src = (const float4*)(h + off);
            unsigned short tmp[16];
#pragma unroll
            for (int j = 0; j < 4; ++j) {
                float4 v = src[j];
                tmp[j*4+0]=f2bf(v.x); tmp[j*4+1]=f2bf(v.y);
                tmp[j*4+2]=f2bf(v.z); tmp[j*4+3]=f2bf(v.w);
            }
            *(u16x8*)(hb + off)     = *(const u16x8*)&tmp[0];
            *(u16x8*)(hb + off + 8) = *(const u16x8*)&tmp[8];
        }
    }
}

__global__ void edge_max_kernel(const int* __restrict__ edges, int* __restrict__ ws) {
    int e = blockIdx.x * 256 + threadIdx.x;
    if (e < N_EDGES) atomicMax(&ws[OFF_LAST + edges[e * 3 + 2]], e);
}

// ---------- fused bucket + self GEMM (bf16 MFMA) ----------
#define BUCKET_BLKS 196
#define NODE_TILES 782

__global__ __launch_bounds__(256) void bucket_self_kernel(
    const int* __restrict__ edges, const unsigned short* __restrict__ hb,
    const unsigned short* __restrict__ wt, int* __restrict__ ws,
    float* __restrict__ out)
{
    __shared__ unsigned short Wsh[DIM * KPAD];
    __shared__ unsigned short Hs[DIM * KPAD];
    int t = threadIdx.x;

    if (blockIdx.x < BUCKET_BLKS) {
        int n = blockIdx.x * 256 + t;
        if (n < N_NODES) {
            int li = ws[OFF_LAST + n];
            if (li >= 0) {
                int r = edges[li * 3 + 1];
                int s = edges[li * 3 + 0];
                int pos = atomicAdd(&ws[OFF_CUR + r], 1);
                if (pos < CAP) {
                    ws[OFF_BN + r * CAP + pos] = n;
                    ws[OFF_BS + r * CAP + pos] = s;
                }
            }
        }
        return;
    }

    int base = (blockIdx.x - BUCKET_BLKS) * 64;
    int row = t >> 2, q = t & 3;
    {
        const unsigned short* wsrc = wt + (size_t)NUM_RELS * DIM * DIM + row * DIM + q * 16;
        *(u16x8*)&Wsh[row * KPAD + q * 16]     = *(const u16x8*)wsrc;
        *(u16x8*)&Wsh[row * KPAD + q * 16 + 8] = *(const u16x8*)(wsrc + 8);
        int n = base + row; if (n >= N_NODES) n = N_NODES - 1;
        const unsigned short* hsrc = hb + (size_t)n * DIM + q * 16;
        *(u16x8*)&Hs[row * KPAD + q * 16]     = *(const u16x8*)hsrc;
        *(u16x8*)&Hs[row * KPAD + q * 16 + 8] = *(const u16x8*)(hsrc + 8);
    }
    __syncthreads();

    int l = t & 63;
    int w = __builtin_amdgcn_readfirstlane(t >> 6);   // wave -> 16-row strip
    int r16 = l & 15, kb = l >> 4;

    bf16x8 a0 = *reinterpret_cast<const bf16x8*>(&Hs[(w * 16 + r16) * KPAD + kb * 8]);
    bf16x8 a1 = *reinterpret_cast<const bf16x8*>(&Hs[(w * 16 + r16) * KPAD + 32 + kb * 8]);

    int nn[4]; bool vv[4];
#pragma unroll
    for (int r = 0; r < 4; ++r) {
        nn[r] = base + w * 16 + kb * 4 + r;           // C row = (l>>4)*4 + r
        vv[r] = nn[r] < N_NODES;
    }

#pragma unroll
    for (int n4 = 0; n4 < 4; ++n4) {
        bf16x8 b0 = *reinterpret_cast<const bf16x8*>(&Wsh[(n4 * 16 + r16) * KPAD + kb * 8]);
        bf16x8 b1 = *reinterpret_cast<const bf16x8*>(&Wsh[(n4 * 16 + r16) * KPAD + 32 + kb * 8]);
        f32x4 acc = {0.f, 0.f, 0.f, 0.f};
        acc = __builtin_amdgcn_mfma_f32_16x16x32_bf16(a0, b0, acc, 0, 0, 0);
        acc = __builtin_amdgcn_mfma_f32_16x16x32_bf16(a1, b1, acc, 0, 0, 0);
#pragma unroll
        for (int r = 0; r < 4; ++r)
            if (vv[r]) out[(size_t)nn[r] * DIM + n4 * 16 + r16] = acc[r];
    }
}

// ---------- msg GEMM (bf16 MFMA): out[n] += h[src] @ W[rel] ----------
__global__ __launch_bounds__(256) void msg_kernel(
    const unsigned short* __restrict__ hb, const unsigned short* __restrict__ wt,
    const int* __restrict__ ws, float* __restrict__ out)
{
    __shared__ unsigned short Wsh[DIM * KPAD];
    __shared__ unsigned short Hs[DIM * KPAD];

    int rel = blockIdx.x >> 3;
    int tile = blockIdx.x & 7;
    int c = ws[OFF_CUR + rel];
    if (c > CAP) c = CAP;
    int start = tile * 64;
    if (start >= c) return;

    int t = threadIdx.x;
    const int* bn = ws + OFF_BN + rel * CAP;
    const int* bs = ws + OFF_BS + rel * CAP;

    int row = t >> 2, q = t & 3;
    {
        const unsigned short* wsrc = wt + (size_t)rel * DIM * DIM + row * DIM + q * 16;
        *(u16x8*)&Wsh[row * KPAD + q * 16]     = *(const u16x8*)wsrc;
        *(u16x8*)&Wsh[row * KPAD + q * 16 + 8] = *(const u16x8*)(wsrc + 8);
        int pos = start + row; if (pos >= c) pos = c - 1;
        int s = bs[pos];
        const unsigned short* hsrc = hb + (size_t)s * DIM + q * 16;
        *(u16x8*)&Hs[row * KPAD + q * 16]     = *(const u16x8*)hsrc;
        *(u16x8*)&Hs[row * KPAD + q * 16 + 8] = *(const u16x8*)(hsrc + 8);
    }
    __syncthreads();

    int l = t & 63;
    int w = __builtin_amdgcn_readfirstlane(t >> 6);
    int r16 = l & 15, kb = l >> 4;

    bf16x8 a0 = *reinterpret_cast<const bf16x8*>(&Hs[(w * 16 + r16) * KPAD + kb * 8]);
    bf16x8 a1 = *reinterpret_cast<const bf16x8*>(&Hs[(w * 16 + r16) * KPAD + 32 + kb * 8]);

    int nn[4]; bool vv[4];
#pragma unroll
    for (int r = 0; r < 4; ++r) {
        int p = start + w * 16 + kb * 4 + r;
        vv[r] = p < c;
        nn[r] = bn[vv[r] ? p : 0];
    }

#pragma unroll
    for (int n4 = 0; n4 < 4; ++n4) {
        bf16x8 b0 = *reinterpret_cast<const bf16x8*>(&Wsh[(n4 * 16 + r16) * KPAD + kb * 8]);
        bf16x8 b1 = *reinterpret_cast<const bf16x8*>(&Wsh[(n4 * 16 + r16) * KPAD + 32 + kb * 8]);
        f32x4 acc = {0.f, 0.f, 0.f, 0.f};
        acc = __builtin_amdgcn_mfma_f32_16x16x32_bf16(a0, b0, acc, 0, 0, 0);
        acc = __builtin_amdgcn_mfma_f32_16x16x32_bf16(a1, b1, acc, 0, 0, 0);
#pragma unroll
        for (int r = 0; r < 4; ++r)
            if (vv[r]) out[(size_t)nn[r] * DIM + n4 * 16 + r16] += acc[r];
    }
}

extern "C" void kernel_launch(void* const* d_in, const int* in_sizes, int n_in,
                              void* d_out, int out_size, void* d_ws, size_t ws_size,
                              hipStream_t stream) {
    const float* h      = (const float*)d_in[0];
    const int*   edges  = (const int*)d_in[1];
    const float* weight = (const float*)d_in[2];
    const float* wself  = (const float*)d_in[3];
    float* out = (float*)d_out;
    int* wsi = (int*)d_ws;
    unsigned short* hb = (unsigned short*)((char*)d_ws + HB_OFF);
    unsigned short* wt = (unsigned short*)((char*)d_ws + WT_OFF);

    prep_kernel<<<PREP_INIT + PREP_WT + PREP_HB, 256, 0, stream>>>(h, weight, wself, wsi, hb, wt);
    edge_max_kernel<<<(N_EDGES + 255) / 256, 256, 0, stream>>>(edges, wsi);
    bucket_self_kernel<<<BUCKET_BLKS + NODE_TILES, 256, 0, stream>>>(edges, hb, wt, wsi, out);
    msg_kernel<<<NUM_RELS * TILES, 256, 0, stream>>>(hb, wt, wsi, out);
}